// Round 12
// baseline (210.292 us; speedup 1.0000x reference)
//
#include <hip/hip_runtime.h>
#include <hip/hip_bf16.h>
#include <cstdint>
#include <cstddef>

#define N_TOK 4096
#define DM    1024
#define DH    2048
#define NE    8
#define BM    128
#define BN1   256            // gemm1 tile cols
#define BN2   128            // gemm2 tile cols
#define BK    64
#define MAXT  80
#define TPXM  ((MAXT + 7) / 8)
#define HROWS (MAXT * BM)

typedef unsigned short u16t;
typedef __attribute__((ext_vector_type(4))) float          f32x4;
typedef __attribute__((ext_vector_type(8))) unsigned short u16x8;

__device__ __forceinline__ u16t f2b(float f) {
  union { float f; unsigned u; } v; v.f = f;
  return (u16t)((v.u + 0x7FFFu + ((v.u >> 16) & 1u)) >> 16);
}

__device__ __forceinline__ void gload16(const void* g, void* l) {
  auto gp = (const __attribute__((address_space(1))) unsigned int*)(uintptr_t)g;
  auto lp = (__attribute__((address_space(3))) unsigned int*)(uintptr_t)l;
  __builtin_amdgcn_global_load_lds(gp, lp, 16, 0, 0);
}

__device__ __forceinline__ void mfma16(f32x4& c, u16x8 a, u16x8 b) {
  asm("v_mfma_f32_16x16x32_bf16 %0, %1, %2, %0" : "+v"(c) : "v"(a), "v"(b));
}

// ============ fused prologue: tr_cvt(w1) | tr_cvt(w2) | gate(+x->bf16) ============
__global__ void __launch_bounds__(256) k_prep(
    const float* __restrict__ x,  const float* __restrict__ gw,
    const float* __restrict__ w1, const float* __restrict__ w2,
    u16t* __restrict__ x16, u16t* __restrict__ w1t, u16t* __restrict__ w2t,
    int* __restrict__ topi, float* __restrict__ topg) {
  __shared__ float smem[NE * DM];
  int b = blockIdx.x;
  int tid = threadIdx.x;
  if (b < 8192) {
    const float* src; u16t* dst; int R, C, bx, by, bz;
    if (b < 4096) {
      int l = b; bz = l >> 9; int rem = l & 511;
      R = DM; C = DH; bx = rem & 31; by = rem >> 5; src = w1; dst = w1t;
    } else {
      int l = b - 4096; bz = l >> 9; int rem = l & 511;
      R = DH; C = DM; bx = rem & 15; by = rem >> 4; src = w2; dst = w2t;
    }
    float (*t)[65] = reinterpret_cast<float(*)[65]>(smem);
    const float* s = src + (size_t)bz * R * C;
    u16t* d = dst + (size_t)bz * R * C;
    int r0 = by * 64, c0 = bx * 64;
#pragma unroll
    for (int i = 0; i < 16; ++i) {
      int idx = i * 256 + tid;
      int r = idx >> 6, c = idx & 63;
      t[r][c] = s[(size_t)(r0 + r) * C + (c0 + c)];
    }
    __syncthreads();
#pragma unroll
    for (int i = 0; i < 16; ++i) {
      int idx = i * 256 + tid;
      int rr = idx >> 6, cc = idx & 63;
      d[(size_t)(c0 + rr) * R + (r0 + cc)] = f2b(t[cc][rr]);
    }
  } else {
    float* gws = smem;
#pragma unroll
    for (int i = 0; i < NE * DM / 256; ++i) gws[i * 256 + tid] = gw[i * 256 + tid];
    __syncthreads();
    int wv = tid >> 6, lane = tid & 63;
    int t = (b - 8192) * 4 + wv;
    float acc[NE];
#pragma unroll
    for (int e = 0; e < NE; ++e) acc[e] = 0.f;
    const float* xr = x + (size_t)t * DM;
    u16t* xo = x16 + (size_t)t * DM;
#pragma unroll
    for (int c = 0; c < DM / 64; ++c) {
      float xv = xr[c * 64 + lane];
      xo[c * 64 + lane] = f2b(xv);
#pragma unroll
      for (int e = 0; e < NE; ++e) acc[e] += xv * gws[e * DM + c * 64 + lane];
    }
#pragma unroll
    for (int e = 0; e < NE; ++e) {
#pragma unroll
      for (int m = 1; m < 64; m <<= 1) acc[e] += __shfl_xor(acc[e], m);
    }
    float mx = acc[0];
#pragma unroll
    for (int e = 1; e < NE; ++e) mx = fmaxf(mx, acc[e]);
    float p[NE], s = 0.f;
#pragma unroll
    for (int e = 0; e < NE; ++e) { p[e] = expf(acc[e] - mx); s += p[e]; }
    float inv = 1.f / s;
#pragma unroll
    for (int e = 0; e < NE; ++e) p[e] *= inv;
    int i1 = 0; float g1 = p[0];
#pragma unroll
    for (int e = 1; e < NE; ++e) if (p[e] > g1) { g1 = p[e]; i1 = e; }
    int i2 = -1; float g2 = -1.f;
#pragma unroll
    for (int e = 0; e < NE; ++e) if (e != i1 && p[e] > g2) { g2 = p[e]; i2 = e; }
    if (lane == 0) {
      topi[t * 2 + 0] = i1; topi[t * 2 + 1] = i2;
      topg[t * 2 + 0] = g1; topg[t * 2 + 1] = g2;
    }
  }
}

// ------- merged histogram + scan + tile table (1 block, 1024 threads) -------
__global__ void __launch_bounds__(1024) k_scan(const int* __restrict__ topi,
                                               int* __restrict__ offe,
                                               int* __restrict__ cur64,
                                               int* __restrict__ te,
                                               int* __restrict__ trs,
                                               int* __restrict__ tnr,
                                               int* __restrict__ ntiles) {
  __shared__ int hist[NE];
  int tid = threadIdx.x;
  if (tid < NE) { hist[tid] = 0; cur64[tid * 16] = 0; }
  __syncthreads();
  int lc[NE];
#pragma unroll
  for (int e = 0; e < NE; ++e) lc[e] = 0;
#pragma unroll
  for (int i = 0; i < (N_TOK * 2) / 1024; ++i) {
    int v = topi[tid * ((N_TOK * 2) / 1024) + i];
#pragma unroll
    for (int e = 0; e < NE; ++e) lc[e] += (v == e);
  }
#pragma unroll
  for (int e = 0; e < NE; ++e) {
#pragma unroll
    for (int m = 1; m < 64; m <<= 1) lc[e] += __shfl_xor(lc[e], m);
  }
  if ((tid & 63) == 0) {
#pragma unroll
    for (int e = 0; e < NE; ++e) atomicAdd(&hist[e], lc[e]);
  }
  __syncthreads();
  if (tid == 0) {
    int off = 0, nt = 0;
    for (int e = 0; e < NE; ++e) {
      offe[e] = off;
      int c = hist[e];
      for (int i = 0; i < c; i += BM) {
        te[nt] = e; trs[nt] = off + i; tnr[nt] = min(BM, c - i); ++nt;
      }
      off += c;
    }
    *ntiles = nt;
  }
}

// ------- scatter with wave-aggregated atomics, padded counters -------
__global__ void k_scatter(const int* __restrict__ topi, const int* __restrict__ offe,
                          int* __restrict__ cur64, int* __restrict__ pair) {
  int t = blockIdx.x * blockDim.x + threadIdx.x;
  int lane = threadIdx.x & 63;
#pragma unroll
  for (int s = 0; s < 2; ++s) {
    int e = topi[t * 2 + s];
    int pos = 0;
#pragma unroll
    for (int ee = 0; ee < NE; ++ee) {
      unsigned long long mask = __ballot(e == ee);
      if (e == ee) {
        int rank = __popcll(mask & ((1ull << lane) - 1ull));
        int leader = __ffsll((long long)mask) - 1;
        int base = 0;
        if (lane == leader) base = atomicAdd(&cur64[ee * 16], (int)__popcll(mask));
        base = __shfl(base, leader);
        pos = offe[ee] + base + rank;
      }
    }
    pair[pos] = t * 2 + s;
  }
}

// -------- GEMM1: 128x256 tile, 512 thr / 8 waves (2Mx4N), PLAIN 2D grid --------
// R9 showed the plain mapping runs the L3 staging pipe at 100%; BN1=256 cuts
// staged bytes 512->418 MB. No XCD banding here (it cost 8-9% in R10/R11).
__global__ void __launch_bounds__(512, 4) k_gemm1(
    const u16t* __restrict__ x16, const u16t* __restrict__ w1t,
    const float* __restrict__ b1, u16t* __restrict__ h16,
    const int* __restrict__ pair, const int* __restrict__ te,
    const int* __restrict__ trs, const int* __restrict__ tnr,
    const int* __restrict__ ntiles) {
  int ty = blockIdx.y;
  if (ty >= *ntiles) return;
  int e = te[ty], rs = trs[ty], nr = tnr[ty];
  int n0 = blockIdx.x * BN1;
  __shared__ u16t As[BM * BK];
  __shared__ u16t Bs[BN1 * BK];
  __shared__ int tok[BM];
  int tid = threadIdx.x;
  if (tid < BM) {
    int p = rs + (tid < nr ? tid : nr - 1);
    tok[tid] = pair[p] >> 1;
  }
  __syncthreads();
  const u16t* aptr[2]; const u16t* bptr[4];
#pragma unroll
  for (int it = 0; it < 2; ++it) {
    int idx = it * 512 + tid;
    int r = idx >> 3, c = idx & 7;
    int cs = c ^ (r & 7);
    aptr[it] = x16 + (size_t)tok[r] * DM + cs * 8;
  }
#pragma unroll
  for (int it = 0; it < 4; ++it) {
    int idx = it * 512 + tid;
    int r = idx >> 3, c = idx & 7;
    int cs = c ^ (r & 7);
    bptr[it] = w1t + (size_t)e * DH * DM + (size_t)(n0 + r) * DM + cs * 8;
  }
  f32x4 acc[4][4];
#pragma unroll
  for (int m = 0; m < 4; ++m)
#pragma unroll
    for (int n = 0; n < 4; ++n) acc[m][n] = {0.f, 0.f, 0.f, 0.f};
  int lane = tid & 63, wv = tid >> 6;
  int wr = (wv >> 2) * 64, wc = (wv & 3) * 64;   // 2M x 4N wave grid
  for (int k0 = 0; k0 < DM; k0 += BK) {
#pragma unroll
    for (int it = 0; it < 2; ++it) {
      int idx = it * 512 + tid;
      gload16(aptr[it] + k0, &As[idx * 8]);
    }
#pragma unroll
    for (int it = 0; it < 4; ++it) {
      int idx = it * 512 + tid;
      gload16(bptr[it] + k0, &Bs[idx * 8]);
    }
    __syncthreads();
#pragma unroll
    for (int kk = 0; kk < 2; ++kk) {
      u16x8 af[4], bf[4];
#pragma unroll
      for (int m = 0; m < 4; ++m) {
        int row = wr + m * 16 + (lane & 15);
        int cs = (kk * 4 + (lane >> 4)) ^ (row & 7);
        af[m] = *reinterpret_cast<const u16x8*>(&As[row * BK + cs * 8]);
      }
#pragma unroll
      for (int n = 0; n < 4; ++n) {
        int row = wc + n * 16 + (lane & 15);
        int cs = (kk * 4 + (lane >> 4)) ^ (row & 7);
        bf[n] = *reinterpret_cast<const u16x8*>(&Bs[row * BK + cs * 8]);
      }
#pragma unroll
      for (int m = 0; m < 4; ++m)
#pragma unroll
        for (int n = 0; n < 4; ++n) mfma16(acc[m][n], af[m], bf[n]);
    }
    __syncthreads();
  }
#pragma unroll
  for (int n = 0; n < 4; ++n) {
    int col = n0 + wc + n * 16 + (lane & 15);
    float bias = b1[e * DH + col];
#pragma unroll
    for (int m = 0; m < 4; ++m) {
#pragma unroll
      for (int r = 0; r < 4; ++r) {
        int rl = wr + m * 16 + ((lane >> 4) << 2) + r;
        if (rl < nr) {
          float z = acc[m][n][r] + bias;
          float g = 0.5f * z * (1.0f + erff(z * 0.70710678118654752440f));
          h16[(size_t)(rs + rl) * DH + col] = f2b(g);
        }
      }
    }
  }
}

// -------- GEMM2: R10 body (128x128, 256 thr), dynamic INTERLEAVED XCD banding --------
// ty = i*8 + xcd: balance +-1 tile; co-resident same-XCD blocks group by n0
// (B col-panel L2-hot) and the h-band stays XCD-local.
__global__ void __launch_bounds__(256, 2) k_gemm2(
    const u16t* __restrict__ h16, const u16t* __restrict__ w2t,
    const float* __restrict__ b2, float* __restrict__ out,
    const int* __restrict__ pair, const float* __restrict__ topg,
    const int* __restrict__ te, const int* __restrict__ trs,
    const int* __restrict__ tnr, const int* __restrict__ ntiles) {
  int nt = *ntiles;
  int b = blockIdx.x;
  int xcd = b & 7, elem = b >> 3;
  int tpx = (nt + 7) >> 3;
  if (elem >= tpx * (DM / BN2)) return;
  int ty = (elem % tpx) * 8 + xcd;
  if (ty >= nt) return;
  int n0 = (elem / tpx) * BN2;
  int e = te[ty], rs = trs[ty], nr = tnr[ty];
  __shared__ u16t As[BM * BK];
  __shared__ u16t Bs[BN2 * BK];
  __shared__ int tsl[BM];
  __shared__ float gl[BM];
  int tid = threadIdx.x;
  if (tid < BM) {
    int p = rs + (tid < nr ? tid : nr - 1);
    int ts = pair[p];
    tsl[tid] = ts;
    gl[tid] = topg[ts];
  }
  __syncthreads();
  const u16t* aptr[4]; const u16t* bptr[4];
#pragma unroll
  for (int it = 0; it < 4; ++it) {
    int idx = it * 256 + tid;
    int r = idx >> 3, c = idx & 7;
    int cs = c ^ (r & 7);
    aptr[it] = h16 + (size_t)(rs + r) * DH + cs * 8;
    bptr[it] = w2t + (size_t)e * DM * DH + (size_t)(n0 + r) * DH + cs * 8;
  }
  f32x4 acc[4][4];
#pragma unroll
  for (int m = 0; m < 4; ++m)
#pragma unroll
    for (int n = 0; n < 4; ++n) acc[m][n] = {0.f, 0.f, 0.f, 0.f};
  int lane = tid & 63, wv = tid >> 6;
  int wr = (wv >> 1) * 64, wc = (wv & 1) * 64;
  for (int k0 = 0; k0 < DH; k0 += BK) {
#pragma unroll
    for (int it = 0; it < 4; ++it) {
      int idx = it * 256 + tid;
      gload16(aptr[it] + k0, &As[idx * 8]);
      gload16(bptr[it] + k0, &Bs[idx * 8]);
    }
    __syncthreads();
#pragma unroll
    for (int kk = 0; kk < 2; ++kk) {
      u16x8 af[4], bf[4];
#pragma unroll
      for (int m = 0; m < 4; ++m) {
        int row = wr + m * 16 + (lane & 15);
        int cs = (kk * 4 + (lane >> 4)) ^ (row & 7);
        af[m] = *reinterpret_cast<const u16x8*>(&As[row * BK + cs * 8]);
      }
#pragma unroll
      for (int n = 0; n < 4; ++n) {
        int row = wc + n * 16 + (lane & 15);
        int cs = (kk * 4 + (lane >> 4)) ^ (row & 7);
        bf[n] = *reinterpret_cast<const u16x8*>(&Bs[row * BK + cs * 8]);
      }
#pragma unroll
      for (int m = 0; m < 4; ++m)
#pragma unroll
        for (int n = 0; n < 4; ++n) mfma16(acc[m][n], af[m], bf[n]);
    }
    __syncthreads();
  }
  float bias[4];
#pragma unroll
  for (int n = 0; n < 4; ++n) bias[n] = b2[e * DM + n0 + wc + n * 16 + (lane & 15)];
#pragma unroll
  for (int m = 0; m < 4; ++m) {
#pragma unroll
    for (int r = 0; r < 4; ++r) {
      int rl = wr + m * 16 + ((lane >> 4) << 2) + r;
      if (rl < nr) {
        int ts = tsl[rl];
        float g = gl[rl];
        float* orow = out + (size_t)(ts >> 1) * DM;
#pragma unroll
        for (int n = 0; n < 4; ++n) {
          int col = n0 + wc + n * 16 + (lane & 15);
          float v = g * (acc[m][n][r] + bias[n]);
          unsafeAtomicAdd(&orow[col], v);
        }
      }
    }
  }
}

extern "C" void kernel_launch(void* const* d_in, const int* in_sizes, int n_in,
                              void* d_out, int out_size, void* d_ws, size_t ws_size,
                              hipStream_t stream) {
  const float* x  = (const float*)d_in[0];
  const float* gw = (const float*)d_in[1];
  const float* w1 = (const float*)d_in[2];
  const float* b1 = (const float*)d_in[3];
  const float* w2 = (const float*)d_in[4];
  const float* b2 = (const float*)d_in[5];
  float* out = (float*)d_out;
  char* ws = (char*)d_ws;

  size_t o = 0;
  auto alloc = [&](size_t b) { size_t p = o; o += (b + 255) & ~(size_t)255; return p; };
  size_t X16  = alloc((size_t)N_TOK * DM * 2);
  size_t W1T  = alloc((size_t)NE * DH * DM * 2);
  size_t W2T  = alloc((size_t)NE * DM * DH * 2);
  size_t HB   = alloc((size_t)HROWS * DH * 2);
  size_t TOPI = alloc((size_t)N_TOK * 2 * 4);
  size_t TOPG = alloc((size_t)N_TOK * 2 * 4);
  size_t PAIR = alloc((size_t)HROWS * 4);
  size_t CUR  = alloc(NE * 64);
  size_t OFE  = alloc(64);
  size_t TE   = alloc(MAXT * 4);
  size_t TRS  = alloc(MAXT * 4);
  size_t TNR  = alloc(MAXT * 4);
  size_t NT   = alloc(64);
  (void)ws_size; (void)in_sizes; (void)n_in;

  hipMemsetAsync(out, 0, (size_t)out_size * 4, stream);

  k_prep<<<8192 + N_TOK / 4, 256, 0, stream>>>(
      x, gw, w1, w2, (u16t*)(ws + X16), (u16t*)(ws + W1T), (u16t*)(ws + W2T),
      (int*)(ws + TOPI), (float*)(ws + TOPG));
  k_scan<<<1, 1024, 0, stream>>>((int*)(ws + TOPI), (int*)(ws + OFE), (int*)(ws + CUR),
                                 (int*)(ws + TE), (int*)(ws + TRS), (int*)(ws + TNR),
                                 (int*)(ws + NT));
  k_scatter<<<N_TOK / 256, 256, 0, stream>>>((int*)(ws + TOPI), (int*)(ws + OFE),
                                             (int*)(ws + CUR), (int*)(ws + PAIR));
  k_gemm1<<<dim3(DH / BN1, MAXT), 512, 0, stream>>>(
      (const u16t*)(ws + X16), (const u16t*)(ws + W1T), b1, (u16t*)(ws + HB),
      (const int*)(ws + PAIR), (const int*)(ws + TE), (const int*)(ws + TRS),
      (const int*)(ws + TNR), (const int*)(ws + NT));
  k_gemm2<<<8 * TPXM * (DM / BN2), 256, 0, stream>>>(
      (const u16t*)(ws + HB), (const u16t*)(ws + W2T), b2, out,
      (const int*)(ws + PAIR), (const float*)(ws + TOPG), (const int*)(ws + TE),
      (const int*)(ws + TRS), (const int*)(ws + TNR), (const int*)(ws + NT));
}

// Round 13
// 200.162 us; speedup vs baseline: 1.0506x; 1.0506x over previous
//
#include <hip/hip_runtime.h>
#include <hip/hip_bf16.h>
#include <cstdint>
#include <cstddef>

#define N_TOK 4096
#define DM    1024
#define DH    2048
#define NE    8
#define BM    128
#define BN1   128            // gemm1 tile cols (best measured: R9)
#define BN2   256            // gemm2 tile cols (best measured: R10)
#define BK    64
#define MAXT  80
#define TPXM  ((MAXT + 7) / 8)
#define HROWS (MAXT * BM)

typedef unsigned short u16t;
typedef __attribute__((ext_vector_type(4))) float          f32x4;
typedef __attribute__((ext_vector_type(8))) unsigned short u16x8;

__device__ __forceinline__ u16t f2b(float f) {
  union { float f; unsigned u; } v; v.f = f;
  return (u16t)((v.u + 0x7FFFu + ((v.u >> 16) & 1u)) >> 16);
}

__device__ __forceinline__ void gload16(const void* g, void* l) {
  auto gp = (const __attribute__((address_space(1))) unsigned int*)(uintptr_t)g;
  auto lp = (__attribute__((address_space(3))) unsigned int*)(uintptr_t)l;
  __builtin_amdgcn_global_load_lds(gp, lp, 16, 0, 0);
}

__device__ __forceinline__ void mfma16(f32x4& c, u16x8 a, u16x8 b) {
  asm("v_mfma_f32_16x16x32_bf16 %0, %1, %2, %0" : "+v"(c) : "v"(a), "v"(b));
}

// ============ fused prologue: tr_cvt(w1) | tr_cvt(w2) | gate(+x->bf16) ============
__global__ void __launch_bounds__(256) k_prep(
    const float* __restrict__ x,  const float* __restrict__ gw,
    const float* __restrict__ w1, const float* __restrict__ w2,
    u16t* __restrict__ x16, u16t* __restrict__ w1t, u16t* __restrict__ w2t,
    int* __restrict__ topi, float* __restrict__ topg) {
  __shared__ float smem[NE * DM];
  int b = blockIdx.x;
  int tid = threadIdx.x;
  if (b < 8192) {
    const float* src; u16t* dst; int R, C, bx, by, bz;
    if (b < 4096) {
      int l = b; bz = l >> 9; int rem = l & 511;
      R = DM; C = DH; bx = rem & 31; by = rem >> 5; src = w1; dst = w1t;
    } else {
      int l = b - 4096; bz = l >> 9; int rem = l & 511;
      R = DH; C = DM; bx = rem & 15; by = rem >> 4; src = w2; dst = w2t;
    }
    float (*t)[65] = reinterpret_cast<float(*)[65]>(smem);
    const float* s = src + (size_t)bz * R * C;
    u16t* d = dst + (size_t)bz * R * C;
    int r0 = by * 64, c0 = bx * 64;
#pragma unroll
    for (int i = 0; i < 16; ++i) {
      int idx = i * 256 + tid;
      int r = idx >> 6, c = idx & 63;
      t[r][c] = s[(size_t)(r0 + r) * C + (c0 + c)];
    }
    __syncthreads();
#pragma unroll
    for (int i = 0; i < 16; ++i) {
      int idx = i * 256 + tid;
      int rr = idx >> 6, cc = idx & 63;
      d[(size_t)(c0 + rr) * R + (r0 + cc)] = f2b(t[cc][rr]);
    }
  } else {
    float* gws = smem;
#pragma unroll
    for (int i = 0; i < NE * DM / 256; ++i) gws[i * 256 + tid] = gw[i * 256 + tid];
    __syncthreads();
    int wv = tid >> 6, lane = tid & 63;
    int t = (b - 8192) * 4 + wv;
    float acc[NE];
#pragma unroll
    for (int e = 0; e < NE; ++e) acc[e] = 0.f;
    const float* xr = x + (size_t)t * DM;
    u16t* xo = x16 + (size_t)t * DM;
#pragma unroll
    for (int c = 0; c < DM / 64; ++c) {
      float xv = xr[c * 64 + lane];
      xo[c * 64 + lane] = f2b(xv);
#pragma unroll
      for (int e = 0; e < NE; ++e) acc[e] += xv * gws[e * DM + c * 64 + lane];
    }
#pragma unroll
    for (int e = 0; e < NE; ++e) {
#pragma unroll
      for (int m = 1; m < 64; m <<= 1) acc[e] += __shfl_xor(acc[e], m);
    }
    float mx = acc[0];
#pragma unroll
    for (int e = 1; e < NE; ++e) mx = fmaxf(mx, acc[e]);
    float p[NE], s = 0.f;
#pragma unroll
    for (int e = 0; e < NE; ++e) { p[e] = expf(acc[e] - mx); s += p[e]; }
    float inv = 1.f / s;
#pragma unroll
    for (int e = 0; e < NE; ++e) p[e] *= inv;
    int i1 = 0; float g1 = p[0];
#pragma unroll
    for (int e = 1; e < NE; ++e) if (p[e] > g1) { g1 = p[e]; i1 = e; }
    int i2 = -1; float g2 = -1.f;
#pragma unroll
    for (int e = 0; e < NE; ++e) if (e != i1 && p[e] > g2) { g2 = p[e]; i2 = e; }
    if (lane == 0) {
      topi[t * 2 + 0] = i1; topi[t * 2 + 1] = i2;
      topg[t * 2 + 0] = g1; topg[t * 2 + 1] = g2;
    }
  }
}

// ------- merged histogram + scan + tile table (1 block, 1024 threads) -------
__global__ void __launch_bounds__(1024) k_scan(const int* __restrict__ topi,
                                               int* __restrict__ offe,
                                               int* __restrict__ cur64,
                                               int* __restrict__ te,
                                               int* __restrict__ trs,
                                               int* __restrict__ tnr,
                                               int* __restrict__ ntiles) {
  __shared__ int hist[NE];
  int tid = threadIdx.x;
  if (tid < NE) { hist[tid] = 0; cur64[tid * 16] = 0; }
  __syncthreads();
  int lc[NE];
#pragma unroll
  for (int e = 0; e < NE; ++e) lc[e] = 0;
#pragma unroll
  for (int i = 0; i < (N_TOK * 2) / 1024; ++i) {
    int v = topi[tid * ((N_TOK * 2) / 1024) + i];
#pragma unroll
    for (int e = 0; e < NE; ++e) lc[e] += (v == e);
  }
#pragma unroll
  for (int e = 0; e < NE; ++e) {
#pragma unroll
    for (int m = 1; m < 64; m <<= 1) lc[e] += __shfl_xor(lc[e], m);
  }
  if ((tid & 63) == 0) {
#pragma unroll
    for (int e = 0; e < NE; ++e) atomicAdd(&hist[e], lc[e]);
  }
  __syncthreads();
  if (tid == 0) {
    int off = 0, nt = 0;
    for (int e = 0; e < NE; ++e) {
      offe[e] = off;
      int c = hist[e];
      for (int i = 0; i < c; i += BM) {
        te[nt] = e; trs[nt] = off + i; tnr[nt] = min(BM, c - i); ++nt;
      }
      off += c;
    }
    *ntiles = nt;
  }
}

// ------- scatter with wave-aggregated atomics, padded counters -------
__global__ void k_scatter(const int* __restrict__ topi, const int* __restrict__ offe,
                          int* __restrict__ cur64, int* __restrict__ pair) {
  int t = blockIdx.x * blockDim.x + threadIdx.x;
  int lane = threadIdx.x & 63;
#pragma unroll
  for (int s = 0; s < 2; ++s) {
    int e = topi[t * 2 + s];
    int pos = 0;
#pragma unroll
    for (int ee = 0; ee < NE; ++ee) {
      unsigned long long mask = __ballot(e == ee);
      if (e == ee) {
        int rank = __popcll(mask & ((1ull << lane) - 1ull));
        int leader = __ffsll((long long)mask) - 1;
        int base = 0;
        if (lane == leader) base = atomicAdd(&cur64[ee * 16], (int)__popcll(mask));
        base = __shfl(base, leader);
        pos = offe[ee] + base + rank;
      }
    }
    pair[pos] = t * 2 + s;
  }
}

// -------- GEMM1 (R9-exact, best measured): 128x128, 256 thr, plain 2D grid --------
__global__ void __launch_bounds__(256, 2) k_gemm1(
    const u16t* __restrict__ x16, const u16t* __restrict__ w1t,
    const float* __restrict__ b1, u16t* __restrict__ h16,
    const int* __restrict__ pair, const int* __restrict__ te,
    const int* __restrict__ trs, const int* __restrict__ tnr,
    const int* __restrict__ ntiles) {
  int ty = blockIdx.y;
  if (ty >= *ntiles) return;
  int e = te[ty], rs = trs[ty], nr = tnr[ty];
  int n0 = blockIdx.x * BN1;
  __shared__ u16t As[BM * BK];
  __shared__ u16t Bs[BN1 * BK];
  __shared__ int tok[BM];
  int tid = threadIdx.x;
  if (tid < BM) {
    int p = rs + (tid < nr ? tid : nr - 1);
    tok[tid] = pair[p] >> 1;
  }
  __syncthreads();
  const u16t* aptr[4]; const u16t* bptr[4];
#pragma unroll
  for (int it = 0; it < 4; ++it) {
    int idx = it * 256 + tid;
    int r = idx >> 3, c = idx & 7;
    int cs = c ^ (r & 7);
    aptr[it] = x16 + (size_t)tok[r] * DM + cs * 8;
    bptr[it] = w1t + (size_t)e * DH * DM + (size_t)(n0 + r) * DM + cs * 8;
  }
  f32x4 acc[4][4];
#pragma unroll
  for (int m = 0; m < 4; ++m)
#pragma unroll
    for (int n = 0; n < 4; ++n) acc[m][n] = {0.f, 0.f, 0.f, 0.f};
  int lane = tid & 63, wv = tid >> 6;
  int wr = (wv >> 1) * 64, wc = (wv & 1) * 64;
  for (int k0 = 0; k0 < DM; k0 += BK) {
#pragma unroll
    for (int it = 0; it < 4; ++it) {
      int idx = it * 256 + tid;
      gload16(aptr[it] + k0, &As[idx * 8]);
      gload16(bptr[it] + k0, &Bs[idx * 8]);
    }
    __syncthreads();
#pragma unroll
    for (int kk = 0; kk < 2; ++kk) {
      u16x8 af[4], bf[4];
#pragma unroll
      for (int m = 0; m < 4; ++m) {
        int row = wr + m * 16 + (lane & 15);
        int cs = (kk * 4 + (lane >> 4)) ^ (row & 7);
        af[m] = *reinterpret_cast<const u16x8*>(&As[row * BK + cs * 8]);
      }
#pragma unroll
      for (int n = 0; n < 4; ++n) {
        int row = wc + n * 16 + (lane & 15);
        int cs = (kk * 4 + (lane >> 4)) ^ (row & 7);
        bf[n] = *reinterpret_cast<const u16x8*>(&Bs[row * BK + cs * 8]);
      }
#pragma unroll
      for (int m = 0; m < 4; ++m)
#pragma unroll
        for (int n = 0; n < 4; ++n) mfma16(acc[m][n], af[m], bf[n]);
    }
    __syncthreads();
  }
#pragma unroll
  for (int n = 0; n < 4; ++n) {
    int col = n0 + wc + n * 16 + (lane & 15);
    float bias = b1[e * DH + col];
#pragma unroll
    for (int m = 0; m < 4; ++m) {
#pragma unroll
      for (int r = 0; r < 4; ++r) {
        int rl = wr + m * 16 + ((lane >> 4) << 2) + r;
        if (rl < nr) {
          float z = acc[m][n][r] + bias;
          float g = 0.5f * z * (1.0f + erff(z * 0.70710678118654752440f));
          h16[(size_t)(rs + rl) * DH + col] = f2b(g);
        }
      }
    }
  }
}

// -------- GEMM2 (R10-best): 128x256, 512 thr (2Mx4N), contiguous XCD banding, dynamic tpx --------
__global__ void __launch_bounds__(512, 4) k_gemm2(
    const u16t* __restrict__ h16, const u16t* __restrict__ w2t,
    const float* __restrict__ b2, float* __restrict__ out,
    const int* __restrict__ pair, const float* __restrict__ topg,
    const int* __restrict__ te, const int* __restrict__ trs,
    const int* __restrict__ tnr, const int* __restrict__ ntiles) {
  int nt = *ntiles;
  int b = blockIdx.x;
  int xcd = b & 7, elem = b >> 3;
  int tpx = (nt + 7) >> 3;
  if (elem >= tpx * (DM / BN2)) return;
  int ty = xcd * tpx + (elem % tpx);          // contiguous band per XCD
  if (ty >= nt) return;
  int n0 = (elem / tpx) * BN2;
  int e = te[ty], rs = trs[ty], nr = tnr[ty];
  __shared__ u16t As[BM * BK];
  __shared__ u16t Bs[BN2 * BK];
  __shared__ int tsl[BM];
  __shared__ float gl[BM];
  int tid = threadIdx.x;
  if (tid < BM) {
    int p = rs + (tid < nr ? tid : nr - 1);
    int ts = pair[p];
    tsl[tid] = ts;
    gl[tid] = topg[ts];
  }
  __syncthreads();
  const u16t* aptr[2]; const u16t* bptr[4];
#pragma unroll
  for (int it = 0; it < 2; ++it) {
    int idx = it * 512 + tid;
    int r = idx >> 3, c = idx & 7;
    int cs = c ^ (r & 7);
    aptr[it] = h16 + (size_t)(rs + r) * DH + cs * 8;
  }
#pragma unroll
  for (int it = 0; it < 4; ++it) {
    int idx = it * 512 + tid;
    int r = idx >> 3, c = idx & 7;
    int cs = c ^ (r & 7);
    bptr[it] = w2t + (size_t)e * DM * DH + (size_t)(n0 + r) * DH + cs * 8;
  }
  f32x4 acc[4][4];
#pragma unroll
  for (int m = 0; m < 4; ++m)
#pragma unroll
    for (int n = 0; n < 4; ++n) acc[m][n] = {0.f, 0.f, 0.f, 0.f};
  int lane = tid & 63, wv = tid >> 6;
  int wr = (wv >> 2) * 64, wc = (wv & 3) * 64;   // 2M x 4N wave grid
  for (int k0 = 0; k0 < DH; k0 += BK) {
#pragma unroll
    for (int it = 0; it < 2; ++it) {
      int idx = it * 512 + tid;
      gload16(aptr[it] + k0, &As[idx * 8]);
    }
#pragma unroll
    for (int it = 0; it < 4; ++it) {
      int idx = it * 512 + tid;
      gload16(bptr[it] + k0, &Bs[idx * 8]);
    }
    __syncthreads();
#pragma unroll
    for (int kk = 0; kk < 2; ++kk) {
      u16x8 af[4], bf[4];
#pragma unroll
      for (int m = 0; m < 4; ++m) {
        int row = wr + m * 16 + (lane & 15);
        int cs = (kk * 4 + (lane >> 4)) ^ (row & 7);
        af[m] = *reinterpret_cast<const u16x8*>(&As[row * BK + cs * 8]);
      }
#pragma unroll
      for (int n = 0; n < 4; ++n) {
        int row = wc + n * 16 + (lane & 15);
        int cs = (kk * 4 + (lane >> 4)) ^ (row & 7);
        bf[n] = *reinterpret_cast<const u16x8*>(&Bs[row * BK + cs * 8]);
      }
#pragma unroll
      for (int m = 0; m < 4; ++m)
#pragma unroll
        for (int n = 0; n < 4; ++n) mfma16(acc[m][n], af[m], bf[n]);
    }
    __syncthreads();
  }
  float bias[4];
#pragma unroll
  for (int n = 0; n < 4; ++n) bias[n] = b2[e * DM + n0 + wc + n * 16 + (lane & 15)];
#pragma unroll
  for (int m = 0; m < 4; ++m) {
#pragma unroll
    for (int r = 0; r < 4; ++r) {
      int rl = wr + m * 16 + ((lane >> 4) << 2) + r;
      if (rl < nr) {
        int ts = tsl[rl];
        float g = gl[rl];
        float* orow = out + (size_t)(ts >> 1) * DM;
#pragma unroll
        for (int n = 0; n < 4; ++n) {
          int col = n0 + wc + n * 16 + (lane & 15);
          float v = g * (acc[m][n][r] + bias[n]);
          unsafeAtomicAdd(&orow[col], v);
        }
      }
    }
  }
}

extern "C" void kernel_launch(void* const* d_in, const int* in_sizes, int n_in,
                              void* d_out, int out_size, void* d_ws, size_t ws_size,
                              hipStream_t stream) {
  const float* x  = (const float*)d_in[0];
  const float* gw = (const float*)d_in[1];
  const float* w1 = (const float*)d_in[2];
  const float* b1 = (const float*)d_in[3];
  const float* w2 = (const float*)d_in[4];
  const float* b2 = (const float*)d_in[5];
  float* out = (float*)d_out;
  char* ws = (char*)d_ws;

  size_t o = 0;
  auto alloc = [&](size_t b) { size_t p = o; o += (b + 255) & ~(size_t)255; return p; };
  size_t X16  = alloc((size_t)N_TOK * DM * 2);
  size_t W1T  = alloc((size_t)NE * DH * DM * 2);
  size_t W2T  = alloc((size_t)NE * DM * DH * 2);
  size_t HB   = alloc((size_t)HROWS * DH * 2);
  size_t TOPI = alloc((size_t)N_TOK * 2 * 4);
  size_t TOPG = alloc((size_t)N_TOK * 2 * 4);
  size_t PAIR = alloc((size_t)HROWS * 4);
  size_t CUR  = alloc(NE * 64);
  size_t OFE  = alloc(64);
  size_t TE   = alloc(MAXT * 4);
  size_t TRS  = alloc(MAXT * 4);
  size_t TNR  = alloc(MAXT * 4);
  size_t NT   = alloc(64);
  (void)ws_size; (void)in_sizes; (void)n_in;

  hipMemsetAsync(out, 0, (size_t)out_size * 4, stream);

  k_prep<<<8192 + N_TOK / 4, 256, 0, stream>>>(
      x, gw, w1, w2, (u16t*)(ws + X16), (u16t*)(ws + W1T), (u16t*)(ws + W2T),
      (int*)(ws + TOPI), (float*)(ws + TOPG));
  k_scan<<<1, 1024, 0, stream>>>((int*)(ws + TOPI), (int*)(ws + OFE), (int*)(ws + CUR),
                                 (int*)(ws + TE), (int*)(ws + TRS), (int*)(ws + TNR),
                                 (int*)(ws + NT));
  k_scatter<<<N_TOK / 256, 256, 0, stream>>>((int*)(ws + TOPI), (int*)(ws + OFE),
                                             (int*)(ws + CUR), (int*)(ws + PAIR));
  k_gemm1<<<dim3(DH / BN1, MAXT), 256, 0, stream>>>(
      (const u16t*)(ws + X16), (const u16t*)(ws + W1T), b1, (u16t*)(ws + HB),
      (const int*)(ws + PAIR), (const int*)(ws + TE), (const int*)(ws + TRS),
      (const int*)(ws + TNR), (const int*)(ws + NT));
  k_gemm2<<<8 * TPXM * (DM / BN2), 512, 0, stream>>>(
      (const u16t*)(ws + HB), (const u16t*)(ws + W2T), b2, out,
      (const int*)(ws + PAIR), (const float*)(ws + TOPG), (const int*)(ws + TE),
      (const int*)(ws + TRS), (const int*)(ws + TNR), (const int*)(ws + NT));
}